// Round 8
// baseline (231.870 us; speedup 1.0000x reference)
//
#include <hip/hip_runtime.h>
#include <hip/hip_bf16.h>
#include <cmath>

#define Tt 2048
#define Cc 1024
#define Hh 16
#define HDd 64

typedef __attribute__((ext_vector_type(8))) short short8;
typedef __attribute__((ext_vector_type(4))) float f32x4;
typedef __attribute__((ext_vector_type(16))) float f32x16;

// async global->LDS, 16B per lane; lds base must be wave-uniform
#define ASYNC16(gp, lp)                                       \
    __builtin_amdgcn_global_load_lds(                         \
        (const __attribute__((address_space(1))) void*)(gp),  \
        (__attribute__((address_space(3))) void*)(lp), 16, 0, 0)

__device__ __forceinline__ unsigned short f32_bf16(float f) {
    unsigned u = __float_as_uint(f);
    u += 0x7FFF + ((u >> 16) & 1);
    return (unsigned short)(u >> 16);
}
// 2-op round-to-nearest (ties away) — fine for finite values
__device__ __forceinline__ unsigned short f32_bf16_rn(float f) {
    return (unsigned short)((__float_as_uint(f) + 0x8000u) >> 16);
}
__device__ __forceinline__ float fast_exp2(float x) {
#if __has_builtin(__builtin_amdgcn_exp2f)
    return __builtin_amdgcn_exp2f(x);
#else
    return exp2f(x);
#endif
}

// ---------------- fp32 -> bf16 convert: x + all 4 weights, one launch ----
__global__ __launch_bounds__(256) void cvt_all(
    const float* __restrict__ x, const float* __restrict__ a,
    const float* __restrict__ b, const float* __restrict__ c,
    const float* __restrict__ d, unsigned short* __restrict__ ox,
    unsigned short* __restrict__ oa, unsigned short* __restrict__ ob,
    unsigned short* __restrict__ oc, unsigned short* __restrict__ od) {
    const int id = blockIdx.x * 256 + threadIdx.x;
    const float* src; unsigned short* dst; int sub;
    if (id < 2097152) {
        src = x; dst = ox; sub = id;
    } else {
        const int wi = id - 2097152;
        const int which = wi >> 18;
        sub = wi & 262143;
        if (which == 0)      { src = a; dst = oa; }
        else if (which == 1) { src = b; dst = ob; }
        else if (which == 2) { src = c; dst = oc; }
        else                 { src = d; dst = od; }
    }
    float4 v = ((const float4*)src)[sub];
    ushort4 o;
    o.x = f32_bf16(v.x); o.y = f32_bf16(v.y);
    o.z = f32_bf16(v.z); o.w = f32_bf16(v.w);
    ((ushort4*)dst)[sub] = o;
}

// ---------------- Q|K body: 256x256 4-phase counted-vmcnt ----------------
// (verbatim round-5 gemm_qkv8 body, id passed in; covers N-cols 0..2047)
__device__ __forceinline__ void qk_body(
    unsigned short* lds, const int id,
    const unsigned short* __restrict__ A,
    const unsigned short* __restrict__ Wcat,
    const float* __restrict__ bq, const float* __restrict__ bk,
    unsigned short* __restrict__ qout, unsigned short* __restrict__ kout) {
    const int tid  = threadIdx.x;
    const int wid  = tid >> 6;      // 0..7
    const int lane = tid & 63;
    const int quad = lane >> 4;     // 0..3
    const int lr   = lane & 15;
    const int wr   = wid >> 2;      // 0..1  (M)
    const int wc   = wid & 3;       // 0..3  (N)

    const int xcd  = id & 7;
    const int rank = id >> 3;                 // 0..31
    const int by   = xcd * 4 + (rank >> 3);   // 0..31
    const int bx   = rank & 7;                // 0..7
    const int bm0  = by * 256;
    const int bn0  = bx * 256;                // 0..1792 (Q|K only)

    const int srow  = wid * 8 + (lane >> 3);            // 0..63
    const int scol  = ((lane & 7) ^ (lane >> 3)) * 8;   // swizzled src col
    const int sldso = wid * 512;                        // shorts

    const int a_r   = wr * 64 + lr;
    const int b_r   = wc * 32 + lr;
    const int slot0 = (quad ^ (lr & 7)) * 8;            // ks=0, shorts
    const int slot1 = ((quad ^ 4) ^ (lr & 7)) * 8;      // ks=1

    f32x4 acc[8][4];
    const f32x4 zero = {0.f, 0.f, 0.f, 0.f};
#pragma unroll
    for (int i = 0; i < 8; ++i)
#pragma unroll
        for (int j = 0; j < 4; ++j) acc[i][j] = zero;

    short8 areg[4][2];
    short8 breg[2][2][2];

#define STG(S, BUF, REG, GB, GROW)                                          \
    do {                                                                    \
        if ((S) < 16) {                                                     \
            unsigned short* lb = lds + ((BUF) * 4 + (REG)) * 8192 + sldso;  \
            const unsigned short* gp =                                      \
                (GB) + (size_t)((GROW) + srow) * Cc + (S) * 64 + scol;      \
            ASYNC16(gp, lb);                                                \
            ASYNC16(gp + (size_t)64 * Cc, lb + 4096);                       \
        }                                                                   \
    } while (0)

#define LDA(mh)                                                             \
    do {                                                                    \
        const unsigned short* ab = bufb + (mh) * 8192;                      \
        _Pragma("unroll") for (int mf = 0; mf < 4; ++mf) {                  \
            areg[mf][0] = *(const short8*)(ab + (a_r + mf * 16) * 64 + slot0); \
            areg[mf][1] = *(const short8*)(ab + (a_r + mf * 16) * 64 + slot1); \
        }                                                                   \
    } while (0)

#define LDB(nh)                                                             \
    do {                                                                    \
        const unsigned short* bb = bufb + (2 + (nh)) * 8192;                \
        _Pragma("unroll") for (int nf = 0; nf < 2; ++nf) {                  \
            breg[nh][nf][0] = *(const short8*)(bb + (b_r + nf * 16) * 64 + slot0); \
            breg[nh][nf][1] = *(const short8*)(bb + (b_r + nf * 16) * 64 + slot1); \
        }                                                                   \
    } while (0)

#define MFMA_PHASE(mh, nh)                                                  \
    _Pragma("unroll") for (int mf = 0; mf < 4; ++mf)                        \
    _Pragma("unroll") for (int nf = 0; nf < 2; ++nf) {                      \
        acc[(mh)*4+mf][(nh)*2+nf] = __builtin_amdgcn_mfma_f32_16x16x32_bf16( \
            areg[mf][0], breg[nh][nf][0], acc[(mh)*4+mf][(nh)*2+nf], 0,0,0); \
        acc[(mh)*4+mf][(nh)*2+nf] = __builtin_amdgcn_mfma_f32_16x16x32_bf16( \
            areg[mf][1], breg[nh][nf][1], acc[(mh)*4+mf][(nh)*2+nf], 0,0,0); \
    }

#define TILE(T, BC, WN)                                                     \
    {                                                                       \
        const unsigned short* bufb = lds + (BC) * 32768;                    \
        LDA(0);                                                             \
        LDB(0);                                                             \
        STG((T) + 1, (BC) ^ 1, 1, A, bm0 + 128);                            \
        __builtin_amdgcn_s_barrier();                                       \
        asm volatile("s_waitcnt lgkmcnt(0)" ::: "memory");                  \
        __builtin_amdgcn_s_setprio(1);                                      \
        MFMA_PHASE(0, 0);                                                   \
        __builtin_amdgcn_s_setprio(0);                                      \
        __builtin_amdgcn_s_barrier();                                       \
        LDB(1);                                                             \
        STG((T) + 1, (BC) ^ 1, 3, Wcat, bn0 + 128);                         \
        __builtin_amdgcn_s_barrier();                                       \
        asm volatile("s_waitcnt lgkmcnt(0)" ::: "memory");                  \
        __builtin_amdgcn_s_setprio(1);                                      \
        MFMA_PHASE(0, 1);                                                   \
        __builtin_amdgcn_s_setprio(0);                                      \
        __builtin_amdgcn_s_barrier();                                       \
        LDA(1);                                                             \
        STG((T) + 2, (BC), 0, A, bm0);                                      \
        __builtin_amdgcn_s_barrier();                                       \
        asm volatile("s_waitcnt lgkmcnt(0)" ::: "memory");                  \
        __builtin_amdgcn_s_setprio(1);                                      \
        MFMA_PHASE(1, 0);                                                   \
        __builtin_amdgcn_s_setprio(0);                                      \
        __builtin_amdgcn_s_barrier();                                       \
        STG((T) + 2, (BC), 2, Wcat, bn0);                                   \
        __builtin_amdgcn_s_barrier();                                       \
        __builtin_amdgcn_s_setprio(1);                                      \
        MFMA_PHASE(1, 1);                                                   \
        __builtin_amdgcn_s_setprio(0);                                      \
        asm volatile("s_waitcnt vmcnt(" #WN ")" ::: "memory");              \
        __builtin_amdgcn_s_barrier();                                       \
    }

    STG(0, 0, 0, A, bm0);
    STG(0, 0, 1, A, bm0 + 128);
    STG(0, 0, 2, Wcat, bn0);
    STG(0, 0, 3, Wcat, bn0 + 128);
    STG(1, 1, 0, A, bm0);
    STG(1, 1, 2, Wcat, bn0);
    asm volatile("s_waitcnt vmcnt(4)" ::: "memory");
    __builtin_amdgcn_s_barrier();

    for (int t2 = 0; t2 < 7; ++t2) {
        const int T0 = t2 * 2;
        TILE(T0, 0, 4);
        TILE(T0 + 1, 1, 4);
    }
    TILE(14, 0, 0);
    TILE(15, 1, 0);

#undef TILE
#undef MFMA_PHASE
#undef LDB
#undef LDA
#undef STG

    const int which = bn0 >> 10;  // 0=q 1=k
    const float* bias = (which == 0) ? bq : bk;
    unsigned short* outp = (which == 0) ? qout : kout;
    const float scale = (which == 0) ? 0.1803368801111204f : 1.0f;  // 0.125*log2e
    const int nb = bn0 & 1023;

#pragma unroll
    for (int nh = 0; nh < 2; ++nh)
#pragma unroll
        for (int nf = 0; nf < 2; ++nf) {
            const int nl = nb + nh * 128 + wc * 32 + nf * 16 + lr;
            const float bvv = bias[nl];
            const int h = nl >> 6, hd = nl & 63;
#pragma unroll
            for (int mh = 0; mh < 2; ++mh)
#pragma unroll
                for (int mf = 0; mf < 4; ++mf) {
                    const f32x4 a = acc[mh * 4 + mf][nh * 2 + nf];
                    const int m0 = bm0 + mh * 128 + wr * 64 + mf * 16 + quad * 4;
                    const int b = m0 >> 11, t0 = m0 & 2047;
#pragma unroll
                    for (int r = 0; r < 4; ++r) {
                        outp[(((size_t)(b * Hh + h)) * Tt + t0 + r) * HDd + hd] =
                            f32_bf16_rn((a[r] + bvv) * scale);
                    }
                }
        }
}

// ---------------- V body: 256x128 2-phase (proj8 clone) ------------------
// (verbatim round-5 gemm_v8 body, id passed in; covers Wcat rows 2048..3071)
__device__ __forceinline__ void v_body(
    unsigned short* lds, const int id,
    const unsigned short* __restrict__ A,
    const unsigned short* __restrict__ Wcat,
    const float* __restrict__ bv,
    unsigned short* __restrict__ vout) {
    const int tid  = threadIdx.x;
    const int wid  = tid >> 6;
    const int lane = tid & 63;
    const int quad = lane >> 4;
    const int lr   = lane & 15;
    const int wr   = wid >> 2;      // 0..1
    const int wc   = wid & 3;       // 0..3

    const int xcd  = id & 7;
    const int rank = id >> 3;
    const int by   = xcd * 4 + (rank >> 3);  // 0..31
    const int bx   = rank & 7;               // 0..7
    const int bm0  = by * 256;
    const int wrow0 = 2048 + bx * 128;       // row in Wcat

    const int srow  = wid * 8 + (lane >> 3);
    const int scol  = ((lane & 7) ^ (lane >> 3)) * 8;
    const int sldso = wid * 512;

    const int a_r   = wr * 64 + lr;
    const int b_r2  = (wc & 1) * 32 + lr;
    const int breg_off = 16384 + (wc >> 1) * 4096;
    const int slot0 = (quad ^ (lr & 7)) * 8;
    const int slot1 = ((quad ^ 4) ^ (lr & 7)) * 8;

    f32x4 acc[8][2];
    const f32x4 zero = {0.f, 0.f, 0.f, 0.f};
#pragma unroll
    for (int i = 0; i < 8; ++i)
#pragma unroll
        for (int j = 0; j < 2; ++j) acc[i][j] = zero;

    short8 areg[4][2];
    short8 breg[2][2];

#define STGAV(S, BUF, REG_OFF, GROW)                                        \
    do {                                                                    \
        if ((S) < 16) {                                                     \
            unsigned short* lb = lds + (BUF) * 24576 + (REG_OFF) + sldso;   \
            const unsigned short* gp =                                      \
                A + (size_t)(bm0 + (GROW) + srow) * Cc + (S) * 64 + scol;   \
            ASYNC16(gp, lb);                                                \
            ASYNC16(gp + (size_t)64 * Cc, lb + 4096);                       \
        }                                                                   \
    } while (0)

#define STGBV(S, BUF, REG_OFF, NROW)                                        \
    do {                                                                    \
        if ((S) < 16) {                                                     \
            unsigned short* lb = lds + (BUF) * 24576 + (REG_OFF) + sldso;   \
            const unsigned short* gp =                                      \
                Wcat + (size_t)(wrow0 + (NROW) + srow) * Cc + (S) * 64 + scol; \
            ASYNC16(gp, lb);                                                \
        }                                                                   \
    } while (0)

#define LDA_V(mh)                                                           \
    do {                                                                    \
        const unsigned short* ab = bufb + (mh) * 8192;                      \
        _Pragma("unroll") for (int mf = 0; mf < 4; ++mf) {                  \
            areg[mf][0] = *(const short8*)(ab + (a_r + mf * 16) * 64 + slot0); \
            areg[mf][1] = *(const short8*)(ab + (a_r + mf * 16) * 64 + slot1); \
        }                                                                   \
    } while (0)

#define LDB_V                                                               \
    do {                                                                    \
        const unsigned short* bb = bufb + breg_off;                         \
        _Pragma("unroll") for (int nf = 0; nf < 2; ++nf) {                  \
            breg[nf][0] = *(const short8*)(bb + (b_r2 + nf * 16) * 64 + slot0); \
            breg[nf][1] = *(const short8*)(bb + (b_r2 + nf * 16) * 64 + slot1); \
        }                                                                   \
    } while (0)

#define MFMA_V(mh)                                                          \
    _Pragma("unroll") for (int mf = 0; mf < 4; ++mf)                        \
    _Pragma("unroll") for (int nf = 0; nf < 2; ++nf) {                      \
        acc[(mh)*4+mf][nf] = __builtin_amdgcn_mfma_f32_16x16x32_bf16(       \
            areg[mf][0], breg[nf][0], acc[(mh)*4+mf][nf], 0, 0, 0);         \
        acc[(mh)*4+mf][nf] = __builtin_amdgcn_mfma_f32_16x16x32_bf16(       \
            areg[mf][1], breg[nf][1], acc[(mh)*4+mf][nf], 0, 0, 0);         \
    }

#define TILE_V(T, BC, WN)                                                   \
    {                                                                       \
        const unsigned short* bufb = lds + (BC) * 24576;                    \
        LDA_V(0);                                                           \
        LDB_V;                                                              \
        STGAV((T) + 1, (BC) ^ 1, 8192, 128);                                \
        STGBV((T) + 1, (BC) ^ 1, 20480, 64);                                \
        __builtin_amdgcn_s_barrier();                                       \
        asm volatile("s_waitcnt lgkmcnt(0)" ::: "memory");                  \
        __builtin_amdgcn_s_setprio(1);                                      \
        MFMA_V(0);                                                          \
        __builtin_amdgcn_s_setprio(0);                                      \
        __builtin_amdgcn_s_barrier();                                       \
        LDA_V(1);                                                           \
        STGAV((T) + 2, (BC), 0, 0);                                         \
        STGBV((T) + 2, (BC), 16384, 0);                                     \
        __builtin_amdgcn_s_barrier();                                       \
        asm volatile("s_waitcnt lgkmcnt(0)" ::: "memory");                  \
        __builtin_amdgcn_s_setprio(1);                                      \
        MFMA_V(1);                                                          \
        __builtin_amdgcn_s_setprio(0);                                      \
        asm volatile("s_waitcnt vmcnt(" #WN ")" ::: "memory");              \
        __builtin_amdgcn_s_barrier();                                       \
    }

    STGAV(0, 0, 0, 0);
    STGAV(0, 0, 8192, 128);
    STGBV(0, 0, 16384, 0);
    STGBV(0, 0, 20480, 64);
    STGAV(1, 1, 0, 0);
    STGBV(1, 1, 16384, 0);
    asm volatile("s_waitcnt vmcnt(3)" ::: "memory");
    __builtin_amdgcn_s_barrier();

    for (int t2 = 0; t2 < 7; ++t2) {
        const int T0 = t2 * 2;
        TILE_V(T0, 0, 3);
        TILE_V(T0 + 1, 1, 3);
    }
    TILE_V(14, 0, 0);
    TILE_V(15, 1, 0);

#undef TILE_V
#undef MFMA_V
#undef LDB_V
#undef LDA_V
#undef STGBV
#undef STGAV

    // v epilogue: bf16 [B,H,HD,T], ushort4 along T
#pragma unroll
    for (int nf = 0; nf < 2; ++nf) {
        const int nl = (wrow0 - 2048) + wc * 32 + nf * 16 + lr;  // 0..1023
        const float bvv = bv[nl];
        const int h = nl >> 6, hd = nl & 63;
#pragma unroll
        for (int mh = 0; mh < 2; ++mh)
#pragma unroll
            for (int mf = 0; mf < 4; ++mf) {
                const f32x4 a = acc[mh * 4 + mf][nf];
                const int m0 = bm0 + mh * 128 + wr * 64 + mf * 16 + quad * 4;
                const int b = m0 >> 11, t0 = m0 & 2047;
                ushort4 pk;
                pk.x = f32_bf16_rn(a[0] + bvv);
                pk.y = f32_bf16_rn(a[1] + bvv);
                pk.z = f32_bf16_rn(a[2] + bvv);
                pk.w = f32_bf16_rn(a[3] + bvv);
                *(ushort4*)(vout + (((size_t)(b * Hh + h)) * HDd + hd) * Tt + t0) = pk;
            }
    }
}

// ---------------- fused QKV: one launch, 512 blocks ----------------------
// Round-7: launch-count reduction. Measured ~14 us fixed cost per launch
// (sum-of-dispatches vs wall has been ~70 us / 5 launches every round;
// round-4->5 A/B: +1 launch ate 14 of 17 us kernel savings). id<256 ->
// verified QK body; else verified V body (id-256). Dispatch is x-major so
// QK blocks (gen 1) land first; each CU runs one QK then one V block —
// identical kernel time to the two separate launches, one launch cheaper.
__global__ __launch_bounds__(512, 2) void gemm_fused(
    const unsigned short* __restrict__ A,
    const unsigned short* __restrict__ Wcat,
    const float* __restrict__ bq, const float* __restrict__ bk,
    const float* __restrict__ bv,
    unsigned short* __restrict__ qout, unsigned short* __restrict__ kout,
    unsigned short* __restrict__ vout) {
    extern __shared__ unsigned short lds[];
    const int id = blockIdx.y * 8 + blockIdx.x;  // grid (8,64): 0..511
    if (id < 256)
        qk_body(lds, id, A, Wcat, bq, bk, qout, kout);
    else
        v_body(lds, id - 256, A, Wcat, bv, vout);
}

// ---------------- output projection GEMM: 256x128 2-phase template -------
// (unchanged from round 3 — verified)
__global__ __launch_bounds__(512, 2) void gemm_proj8(
    const unsigned short* __restrict__ A,
    const unsigned short* __restrict__ W,
    const float* __restrict__ bias,
    float* __restrict__ out) {
    extern __shared__ unsigned short lds[];

    const int tid  = threadIdx.x;
    const int wid  = tid >> 6;
    const int lane = tid & 63;
    const int quad = lane >> 4;
    const int lr   = lane & 15;
    const int wr   = wid >> 2;      // 0..1
    const int wc   = wid & 3;       // 0..3

    const int id   = blockIdx.y * 8 + blockIdx.x;
    const int xcd  = id & 7;
    const int rank = id >> 3;          // 0..31
    const int by   = xcd * 4 + (rank >> 3);  // 0..31
    const int bx   = rank & 7;               // 0..7
    const int bm0  = by * 256;
    const int bn0  = bx * 128;

    const int srow  = wid * 8 + (lane >> 3);
    const int scol  = ((lane & 7) ^ (lane >> 3)) * 8;
    const int sldso = wid * 512;

    const int a_r   = wr * 64 + lr;
    const int b_r2  = (wc & 1) * 32 + lr;     // row within own B region
    const int breg_off = 16384 + (wc >> 1) * 4096;  // wave's B region
    const int slot0 = (quad ^ (lr & 7)) * 8;
    const int slot1 = ((quad ^ 4) ^ (lr & 7)) * 8;

    f32x4 acc[8][2];
    const f32x4 zero = {0.f, 0.f, 0.f, 0.f};
#pragma unroll
    for (int i = 0; i < 8; ++i)
#pragma unroll
        for (int j = 0; j < 2; ++j) acc[i][j] = zero;

    short8 areg[4][2];
    short8 breg[2][2];

#define STGA(S, BUF, REG_OFF, GROW)                                         \
    do {                                                                    \
        if ((S) < 16) {                                                     \
            unsigned short* lb = lds + (BUF) * 24576 + (REG_OFF) + sldso;   \
            const unsigned short* gp =                                      \
                A + (size_t)(bm0 + (GROW) + srow) * Cc + (S) * 64 + scol;   \
            ASYNC16(gp, lb);                                                \
            ASYNC16(gp + (size_t)64 * Cc, lb + 4096);                       \
        }                                                                   \
    } while (0)

#define STGB(S, BUF, REG_OFF, NROW)                                         \
    do {                                                                    \
        if ((S) < 16) {                                                     \
            unsigned short* lb = lds + (BUF) * 24576 + (REG_OFF) + sldso;   \
            const unsigned short* gp =                                      \
                W + (size_t)(bn0 + (NROW) + srow) * Cc + (S) * 64 + scol;   \
            ASYNC16(gp, lb);                                                \
        }                                                                   \
    } while (0)

#define LDA_P(mh)                                                           \
    do {                                                                    \
        const unsigned short* ab = bufb + (mh) * 8192;                      \
        _Pragma("unroll") for (int mf = 0; mf < 4; ++mf) {                  \
            areg[mf][0] = *(const short8*)(ab + (a_r + mf * 16) * 64 + slot0); \
            areg[mf][1] = *(const short8*)(ab + (a_r + mf * 16) * 64 + slot1); \
        }                                                                   \
    } while (0)

#define LDB_P                                                               \
    do {                                                                    \
        const unsigned short* bb = bufb + breg_off;                         \
        _Pragma("unroll") for (int nf = 0; nf < 2; ++nf) {                  \
            breg[nf][0] = *(const short8*)(bb + (b_r2 + nf * 16) * 64 + slot0); \
            breg[nf][1] = *(const short8*)(bb + (b_r2 + nf * 16) * 64 + slot1); \
        }                                                                   \
    } while (0)

#define MFMA_P(mh)                                                          \
    _Pragma("unroll") for (int mf = 0; mf < 4; ++mf)                        \
    _Pragma("unroll") for (int nf = 0; nf < 2; ++nf) {                      \
        acc[(mh)*4+mf][nf] = __builtin_amdgcn_mfma_f32_16x16x32_bf16(       \
            areg[mf][0], breg[nf][0], acc[(mh)*4+mf][nf], 0, 0, 0);         \
        acc[(mh)*4+mf][nf] = __builtin_amdgcn_mfma_f32_16x16x32_bf16(       \
            areg[mf][1], breg[nf][1], acc[(mh)*4+mf][nf], 0, 0, 0);         \
    }

#define TILE_P(T, BC, WN)                                                   \
    {                                                                       \
        const unsigned short* bufb = lds + (BC) * 24576;                    \
        LDA_P(0);                                                           \
        LDB_P;                                                              \
        STGA((T) + 1, (BC) ^ 1, 8192, 128);                                 \
        STGB((T) + 1, (BC) ^ 1, 20480, 64);                                 \
        __builtin_amdgcn_s_barrier();                                       \
        asm volatile("s_waitcnt lgkmcnt(0)" ::: "memory");                  \
        __builtin_amdgcn_s_setprio(1);                                      \
        MFMA_P(0);                                                          \
        __builtin_amdgcn_s_setprio(0);                                      \
        __builtin_amdgcn_s_barrier();                                       \
        LDA_P(1);                                                           \
        STGA((T) + 2, (BC), 0, 0);                                          \
        STGB((T) + 2, (BC), 16384, 0);                                      \
        __builtin_amdgcn_s_barrier();                                       \
        asm volatile("s_waitcnt lgkmcnt(0)" ::: "memory");                  \
        __builtin_amdgcn_s_setprio(1);                                      \
        MFMA_P(1);                                                          \
        __builtin_amdgcn_s_setprio(0);                                      \
        asm volatile("s_waitcnt vmcnt(" #WN ")" ::: "memory");              \
        __builtin_amdgcn_s_barrier();                                       \
    }

    STGA(0, 0, 0, 0);
    STGA(0, 0, 8192, 128);
    STGB(0, 0, 16384, 0);
    STGB(0, 0, 20480, 64);
    STGA(1, 1, 0, 0);
    STGB(1, 1, 16384, 0);
    asm volatile("s_waitcnt vmcnt(3)" ::: "memory");
    __builtin_amdgcn_s_barrier();

    for (int t2 = 0; t2 < 7; ++t2) {
        const int T0 = t2 * 2;
        TILE_P(T0, 0, 3);
        TILE_P(T0 + 1, 1, 3);
    }
    TILE_P(14, 0, 0);
    TILE_P(15, 1, 0);

#undef TILE_P
#undef MFMA_P
#undef LDB_P
#undef LDA_P
#undef STGB
#undef STGA

#pragma unroll
    for (int nf = 0; nf < 2; ++nf) {
        const int n = bn0 + wc * 32 + nf * 16 + lr;
        const float bvv = bias[n];
#pragma unroll
        for (int mh = 0; mh < 2; ++mh)
#pragma unroll
            for (int mf = 0; mf < 4; ++mf) {
                const f32x4 a = acc[mh * 4 + mf][nf];
                const int m0 = bm0 + mh * 128 + wr * 64 + mf * 16 + quad * 4;
#pragma unroll
                for (int r = 0; r < 4; ++r)
                    out[(size_t)(m0 + r) * Cc + n] = a[r] + bvv;
            }
    }
}

// ---------------- flash attention: 32x32 MFMA, 4 blocks/CU ---------------
// Round-7: single-pass, grid (64,16) = 1024 blocks x 32 KiB = exactly
// 4 blocks/CU all-co-resident (16 waves/CU = 4 waves/SIMD; round-6 ran
// 2/SIMD, Occupancy 17.8%). Balance: blocks are equal-cost only per
// (head, qt); with all-resident there is no rebalancing, so qt is chosen
// by a permutation making every round-robin CU group {y, y+4, y+8, y+12}
// sum to the same 30: qt = (y&4) ? ((y&8) ? y-12 : y+4) : 15-y
//   -> groups {15,8,7,0} {14,9,6,1} {13,10,5,2} {12,11,4,3}.
// Largest tiles dispatch first (y=0 -> qt=15). Everything inside the
// k-loop is the verified round-6 code (swapped 32x32 QK^T, in-register
// softmax via cvt_pk + permlane32_swap, no P LDS round-trip).
__global__ __launch_bounds__(256, 4) void attn(const unsigned short* __restrict__ q,
                                               const unsigned short* __restrict__ k,
                                               const unsigned short* __restrict__ vt,
                                               unsigned short* __restrict__ y) {
    __shared__ unsigned short sK[2][64 * 64];
    __shared__ unsigned short sV[2][64 * 64];

    const int tid  = threadIdx.x;
    const int wid  = tid >> 6;
    const int lane = tid & 63;
    const int l31  = lane & 31;
    const int hb   = lane >> 5;       // half-wave
    const int x7   = lane & 7;

    const int bh = blockIdx.x;        // head
    const int yb = blockIdx.y;        // 0..15
    const int qt = (yb & 4) ? ((yb & 8) ? yb - 12 : yb + 4) : 15 - yb;
    const size_t headq = (size_t)bh * Tt * HDd;
    const unsigned short* kg = k + headq;
    const unsigned short* vg = vt + headq;
    const int b = bh >> 4, h = bh & 15;

    // staging (verified): each wave stages 16 K rows + 16 V rows per tile
    const int g_r = lane >> 3;                       // 0..7
    const int g_c = ((lane & 7) ^ g_r) * 8;          // pre-swizzled src col
    const unsigned short* kst = kg + (size_t)(wid * 16 + g_r) * HDd + g_c;
    const unsigned short* vst = vg + (size_t)(wid * 16 + g_r) * Tt + g_c;
    unsigned short* dK0 = sK[0] + wid * 1024;
    unsigned short* dK1 = sK[1] + wid * 1024;
    unsigned short* dV0 = sV[0] + wid * 1024;
    unsigned short* dV1 = sV[1] + wid * 1024;

#define STAGE_KV(BUF, KB)                                                   \
    do {                                                                    \
        unsigned short* dK = (BUF) ? dK1 : dK0;                             \
        unsigned short* dV = (BUF) ? dV1 : dV0;                             \
        ASYNC16(kst + (size_t)(KB) * HDd,       dK);                        \
        ASYNC16(kst + (size_t)((KB) + 8) * HDd, dK + 512);                  \
        ASYNC16(vst + (KB),                     dV);                        \
        ASYNC16(vst + (size_t)8 * Tt + (KB),    dV + 512);                  \
    } while (0)

#define CVTPK(d, a, bb) asm("v_cvt_pk_bf16_f32 %0, %1, %2" : "=v"(d) : "v"(a), "v"(bb))
#define PLSWAP(xx, yy)  asm("v_permlane32_swap_b32 %0, %1" : "+v"(xx), "+v"(yy))

    const int frow = l31 * 64;

    const f32x16 zero16 = {0.f,0.f,0.f,0.f,0.f,0.f,0.f,0.f,
                           0.f,0.f,0.f,0.f,0.f,0.f,0.f,0.f};

    const int qb = qt * 128;
    const int ntiles = 2 * qt + 2;
    const int nw = 2 * qt + 1 + (wid >> 1);   // per-wave active tiles

    const unsigned short* qp =
        q + headq + (size_t)(qb + wid * 32 + l31) * HDd;
    short8 qf[4];
#pragma unroll
    for (int c = 0; c < 4; c++)
        qf[c] = *(const short8*)(qp + c * 16 + hb * 8);

    f32x16 o0 = zero16, o1 = zero16;
    float l_run = 0.f;

    STAGE_KV(0, 0);
    __syncthreads();

    for (int kt = 0; kt < ntiles; ++kt) {
        const int cur = kt & 1;
        if (kt + 1 < ntiles) STAGE_KV(cur ^ 1, (kt + 1) * 64);

        if (kt < nw) {
            const unsigned short* bK = sK[cur];
            const unsigned short* bV = sV[cur];

            // QK^T swapped: p0 (k 0..31), p1 (k 32..63)
            f32x16 p0 = zero16, p1 = zero16;
            __builtin_amdgcn_s_setprio(1);
#pragma unroll
            for (int c = 0; c < 4; c++) {
                const int cs = ((2 * c + hb) ^ x7) * 8;
                short8 kf0 = *(const short8*)(bK + frow + cs);
                short8 kf1 = *(const short8*)(bK + 2048 + frow + cs);
                p0 = __builtin_amdgcn_mfma_f32_32x32x16_bf16(kf0, qf[c], p0, 0, 0, 0);
                p1 = __builtin_amdgcn_mfma_f32_32x32x16_bf16(kf1, qf[c], p1, 0, 0, 0);
            }
            __builtin_amdgcn_s_setprio(0);

            // causal mask (only the diagonal tile)
            if (kt == nw - 1 || kt == ntiles - 1) {
                const int qd = qb + wid * 32 + l31 - kt * 64 - 4 * hb;
#pragma unroll
                for (int r = 0; r < 16; r++) {
                    const int kb0 = (r & 3) + 8 * (r >> 2);
                    p0[r] = (kb0 <= qd) ? p0[r] : -INFINITY;
                    p1[r] = (kb0 + 32 <= qd) ? p1[r] : -INFINITY;
                }
            }

            // exp2 + row-sum (in-lane) + pack pairs
            float lacc = 0.f;
#pragma unroll
            for (int r = 0; r < 16; r++) {
                p0[r] = fast_exp2(p0[r]); lacc += p0[r];
                p1[r] = fast_exp2(p1[r]); lacc += p1[r];
            }
            l_run += lacc;

            unsigned w0[4][2], w1[4][2];
#pragma unroll
            for (int g = 0; g < 4; g++) {
                CVTPK(w0[g][0], p0[4 * g + 0], p0[4 * g + 1]);
                CVTPK(w0[g][1], p0[4 * g + 2], p0[4 * g + 3]);
                CVTPK(w1[g][0], p1[4 * g + 0], p1[4 * g + 1]);
                CVTPK(w1[g][1], p1[4 * g + 2], p1[4 * g + 3]);
            }

            // PV: per k-16 chunk kc: A-frag via permlane32_swap, B = V
            __builtin_amdgcn_s_setprio(1);
#pragma unroll
            for (int kc = 0; kc < 4; kc++) {
                unsigned x0, x1, y0, y1;
                if (kc == 0)      { x0 = w0[0][0]; x1 = w0[0][1]; y0 = w0[1][0]; y1 = w0[1][1]; }
                else if (kc == 1) { x0 = w0[2][0]; x1 = w0[2][1]; y0 = w0[3][0]; y1 = w0[3][1]; }
                else if (kc == 2) { x0 = w1[0][0]; x1 = w1[0][1]; y0 = w1[1][0]; y1 = w1[1][1]; }
                else              { x0 = w1[2][0]; x1 = w1[2][1]; y0 = w1[3][0]; y1 = w1[3][1]; }
                PLSWAP(x0, y0);
                PLSWAP(x1, y1);
                union { unsigned u[4]; short8 s; } pu;
                pu.u[0] = x0; pu.u[1] = x1; pu.u[2] = y0; pu.u[3] = y1;

                const int vs = ((2 * kc + hb) ^ x7) * 8;
                short8 vf0 = *(const short8*)(bV + frow + vs);
                short8 vf1 = *(const short8*)(bV + 2048 + frow + vs);
                o0 = __builtin_amdgcn_mfma_f32_32x32x16_bf16(pu.s, vf0, o0, 0, 0, 0);
                o1 = __builtin_amdgcn_mfma_f32_32x32x16_bf16(pu.s, vf1, o1, 0, 0, 0);
            }
            __builtin_amdgcn_s_setprio(0);
        }

        __syncthreads();
    }

    // normalize + write
    l_run += __shfl_xor(l_run, 32);
    const float inv = 1.0f / l_run;
    unsigned short* yp = y + (size_t)(b * Tt + qb + wid * 32) * Cc + h * HDd;
#pragma unroll
    for (int r = 0; r < 16; r++) {
        const int qr = (r & 3) + 8 * (r >> 2) + 4 * hb;
        const float invr = __shfl(inv, qr);
        yp[(size_t)qr * Cc + l31]      = f32_bf16_rn(o0[r] * invr);
        yp[(size_t)qr * Cc + 32 + l31] = f32_bf16_rn(o1[r] * invr);
    }
#undef STAGE_KV
#undef CVTPK
#undef PLSWAP
}

// ---------------- launch ----------------
extern "C" void kernel_launch(void* const* d_in, const int* in_sizes, int n_in,
                              void* d_out, int out_size, void* d_ws, size_t ws_size,
                              hipStream_t stream) {
    const float* x  = (const float*)d_in[0];
    const float* Wk = (const float*)d_in[1];
    const float* bk = (const float*)d_in[2];
    const float* Wq = (const float*)d_in[3];
    const float* bq = (const float*)d_in[4];
    const float* Wv = (const float*)d_in[5];
    const float* bv = (const float*)d_in[6];
    const float* Wp = (const float*)d_in[7];
    const float* bp = (const float*)d_in[8];
    float* out = (float*)d_out;

    char* ws = (char*)d_ws;
    size_t off = 0;
    auto alloc = [&](size_t bytes) { char* p = ws + off; off += bytes; return p; };
    const size_t MK = (size_t)8192 * 1024;
    const size_t NK = (size_t)1024 * 1024;
    unsigned short* xb   = (unsigned short*)alloc(MK * 2);
    unsigned short* Wcat = (unsigned short*)alloc(3 * NK * 2);  // q|k|v contiguous
    unsigned short* Wqb  = Wcat;
    unsigned short* Wkb  = Wcat + NK;
    unsigned short* Wvb  = Wcat + 2 * NK;
    unsigned short* Wpb  = (unsigned short*)alloc(NK * 2);
    unsigned short* qh   = (unsigned short*)alloc(MK * 2);  // [B,H,T,HD], pre-scaled
    unsigned short* kh   = (unsigned short*)alloc(MK * 2);  // [B,H,T,HD]
    unsigned short* vth  = (unsigned short*)alloc(MK * 2);  // [B,H,HD,T]
    unsigned short* ya   = (unsigned short*)alloc(MK * 2);  // [B,T,C]

    static bool lds_attr_set = false;
    if (!lds_attr_set) {
        (void)hipFuncSetAttribute((const void*)gemm_fused,
                                  hipFuncAttributeMaxDynamicSharedMemorySize,
                                  131072);
        (void)hipFuncSetAttribute((const void*)gemm_proj8,
                                  hipFuncAttributeMaxDynamicSharedMemorySize,
                                  98304);
        lds_attr_set = true;
    }

    cvt_all<<<12288, 256, 0, stream>>>(x, Wq, Wk, Wv, Wp, xb, Wqb, Wkb, Wvb, Wpb);

    gemm_fused<<<dim3(8, 64), 512, 131072, stream>>>(xb, Wcat, bq, bk, bv, qh, kh, vth);

    attn<<<dim3(64, 16), 256, 0, stream>>>(qh, kh, vth, ya);

    gemm_proj8<<<dim3(8, 32), 512, 98304, stream>>>(ya, Wpb, bp, out);
}

// Round 9
// 223.856 us; speedup vs baseline: 1.0358x; 1.0358x over previous
//
#include <hip/hip_runtime.h>
#include <hip/hip_bf16.h>
#include <cmath>

#define Tt 2048
#define Cc 1024
#define Hh 16
#define HDd 64

typedef __attribute__((ext_vector_type(8))) short short8;
typedef __attribute__((ext_vector_type(4))) float f32x4;
typedef __attribute__((ext_vector_type(16))) float f32x16;

// async global->LDS, 16B per lane; lds base must be wave-uniform
#define ASYNC16(gp, lp)                                       \
    __builtin_amdgcn_global_load_lds(                         \
        (const __attribute__((address_space(1))) void*)(gp),  \
        (__attribute__((address_space(3))) void*)(lp), 16, 0, 0)

__device__ __forceinline__ unsigned short f32_bf16(float f) {
    unsigned u = __float_as_uint(f);
    u += 0x7FFF + ((u >> 16) & 1);
    return (unsigned short)(u >> 16);
}
// 2-op round-to-nearest (ties away) — fine for finite values
__device__ __forceinline__ unsigned short f32_bf16_rn(float f) {
    return (unsigned short)((__float_as_uint(f) + 0x8000u) >> 16);
}
__device__ __forceinline__ float fast_exp2(float x) {
#if __has_builtin(__builtin_amdgcn_exp2f)
    return __builtin_amdgcn_exp2f(x);
#else
    return exp2f(x);
#endif
}

// ---------------- fp32 -> bf16 convert: x + all 4 weights, one launch ----
__global__ __launch_bounds__(256) void cvt_all(
    const float* __restrict__ x, const float* __restrict__ a,
    const float* __restrict__ b, const float* __restrict__ c,
    const float* __restrict__ d, unsigned short* __restrict__ ox,
    unsigned short* __restrict__ oa, unsigned short* __restrict__ ob,
    unsigned short* __restrict__ oc, unsigned short* __restrict__ od) {
    const int id = blockIdx.x * 256 + threadIdx.x;
    const float* src; unsigned short* dst; int sub;
    if (id < 2097152) {
        src = x; dst = ox; sub = id;
    } else {
        const int wi = id - 2097152;
        const int which = wi >> 18;
        sub = wi & 262143;
        if (which == 0)      { src = a; dst = oa; }
        else if (which == 1) { src = b; dst = ob; }
        else if (which == 2) { src = c; dst = oc; }
        else                 { src = d; dst = od; }
    }
    float4 v = ((const float4*)src)[sub];
    ushort4 o;
    o.x = f32_bf16(v.x); o.y = f32_bf16(v.y);
    o.z = f32_bf16(v.z); o.w = f32_bf16(v.w);
    ((ushort4*)dst)[sub] = o;
}

// ---------------- Q|K body: 256x256 4-phase counted-vmcnt ----------------
// Round-8: read/MFMA overlap. Model (matched measured 60 us): per K-tile
// per CU, LDS frag reads = 192 KB ~= 2260 cyc serialize with MFMA bursts
// ~= 2480 cyc via the lockstep barriers. Changes: (1) LDB(1) hoisted to
// p1 top (breg[1] already allocated -> 0 extra VGPR; reads fly during p1
// MFMA). (2) vmcnt(WN) moved BEFORE p4's MFMA (drain overlaps MFMA;
// earlier wait = still correct). (3) manual lgkmcnt(0) dropped — these are
// compiler-IR loads, hipcc inserts precise counted waits. LDA(1) NOT
// hoisted: acc(128 AGPR)+~120 VGPR leaves no room for a 2nd A set.
__device__ __forceinline__ void qk_body(
    unsigned short* lds, const int id,
    const unsigned short* __restrict__ A,
    const unsigned short* __restrict__ Wcat,
    const float* __restrict__ bq, const float* __restrict__ bk,
    unsigned short* __restrict__ qout, unsigned short* __restrict__ kout) {
    const int tid  = threadIdx.x;
    const int wid  = tid >> 6;      // 0..7
    const int lane = tid & 63;
    const int quad = lane >> 4;     // 0..3
    const int lr   = lane & 15;
    const int wr   = wid >> 2;      // 0..1  (M)
    const int wc   = wid & 3;       // 0..3  (N)

    const int xcd  = id & 7;
    const int rank = id >> 3;                 // 0..31
    const int by   = xcd * 4 + (rank >> 3);   // 0..31
    const int bx   = rank & 7;                // 0..7
    const int bm0  = by * 256;
    const int bn0  = bx * 256;                // 0..1792 (Q|K only)

    const int srow  = wid * 8 + (lane >> 3);            // 0..63
    const int scol  = ((lane & 7) ^ (lane >> 3)) * 8;   // swizzled src col
    const int sldso = wid * 512;                        // shorts

    const int a_r   = wr * 64 + lr;
    const int b_r   = wc * 32 + lr;
    const int slot0 = (quad ^ (lr & 7)) * 8;            // ks=0, shorts
    const int slot1 = ((quad ^ 4) ^ (lr & 7)) * 8;      // ks=1

    f32x4 acc[8][4];
    const f32x4 zero = {0.f, 0.f, 0.f, 0.f};
#pragma unroll
    for (int i = 0; i < 8; ++i)
#pragma unroll
        for (int j = 0; j < 4; ++j) acc[i][j] = zero;

    short8 areg[4][2];
    short8 breg[2][2][2];

#define STG(S, BUF, REG, GB, GROW)                                          \
    do {                                                                    \
        if ((S) < 16) {                                                     \
            unsigned short* lb = lds + ((BUF) * 4 + (REG)) * 8192 + sldso;  \
            const unsigned short* gp =                                      \
                (GB) + (size_t)((GROW) + srow) * Cc + (S) * 64 + scol;      \
            ASYNC16(gp, lb);                                                \
            ASYNC16(gp + (size_t)64 * Cc, lb + 4096);                       \
        }                                                                   \
    } while (0)

#define LDA(mh)                                                             \
    do {                                                                    \
        const unsigned short* ab = bufb + (mh) * 8192;                      \
        _Pragma("unroll") for (int mf = 0; mf < 4; ++mf) {                  \
            areg[mf][0] = *(const short8*)(ab + (a_r + mf * 16) * 64 + slot0); \
            areg[mf][1] = *(const short8*)(ab + (a_r + mf * 16) * 64 + slot1); \
        }                                                                   \
    } while (0)

#define LDB(nh)                                                             \
    do {                                                                    \
        const unsigned short* bb = bufb + (2 + (nh)) * 8192;                \
        _Pragma("unroll") for (int nf = 0; nf < 2; ++nf) {                  \
            breg[nh][nf][0] = *(const short8*)(bb + (b_r + nf * 16) * 64 + slot0); \
            breg[nh][nf][1] = *(const short8*)(bb + (b_r + nf * 16) * 64 + slot1); \
        }                                                                   \
    } while (0)

#define MFMA_PHASE(mh, nh)                                                  \
    _Pragma("unroll") for (int mf = 0; mf < 4; ++mf)                        \
    _Pragma("unroll") for (int nf = 0; nf < 2; ++nf) {                      \
        acc[(mh)*4+mf][(nh)*2+nf] = __builtin_amdgcn_mfma_f32_16x16x32_bf16( \
            areg[mf][0], breg[nh][nf][0], acc[(mh)*4+mf][(nh)*2+nf], 0,0,0); \
        acc[(mh)*4+mf][(nh)*2+nf] = __builtin_amdgcn_mfma_f32_16x16x32_bf16( \
            areg[mf][1], breg[nh][nf][1], acc[(mh)*4+mf][(nh)*2+nf], 0,0,0); \
    }

// Hazard audit for the hoists: LDB(1) reads buf region 3 (B-h1 of T),
// staged at T-1's p2 and resident via T-1's vmcnt(4)+barrier. Its reads
// are drained by p2's MFMA (data dep); the next write of that region is
// T+1's p2 STG, >=3 barriers later. Region 0/1 reads at tile top are
// drained by p1/p3 MFMAs before p3/p4's STGs overwrite them.
#define TILE(T, BC, WN)                                                     \
    {                                                                       \
        const unsigned short* bufb = lds + (BC) * 32768;                    \
        LDA(0);                                                             \
        LDB(0);                                                             \
        LDB(1);                                                             \
        STG((T) + 1, (BC) ^ 1, 1, A, bm0 + 128);                            \
        __builtin_amdgcn_s_barrier();                                       \
        __builtin_amdgcn_s_setprio(1);                                      \
        MFMA_PHASE(0, 0);                                                   \
        __builtin_amdgcn_s_setprio(0);                                      \
        __builtin_amdgcn_s_barrier();                                       \
        STG((T) + 1, (BC) ^ 1, 3, Wcat, bn0 + 128);                         \
        __builtin_amdgcn_s_barrier();                                       \
        __builtin_amdgcn_s_setprio(1);                                      \
        MFMA_PHASE(0, 1);                                                   \
        __builtin_amdgcn_s_setprio(0);                                      \
        __builtin_amdgcn_s_barrier();                                       \
        LDA(1);                                                             \
        STG((T) + 2, (BC), 0, A, bm0);                                      \
        __builtin_amdgcn_s_barrier();                                       \
        __builtin_amdgcn_s_setprio(1);                                      \
        MFMA_PHASE(1, 0);                                                   \
        __builtin_amdgcn_s_setprio(0);                                      \
        __builtin_amdgcn_s_barrier();                                       \
        STG((T) + 2, (BC), 2, Wcat, bn0);                                   \
        __builtin_amdgcn_s_barrier();                                       \
        asm volatile("s_waitcnt vmcnt(" #WN ")" ::: "memory");              \
        __builtin_amdgcn_s_setprio(1);                                      \
        MFMA_PHASE(1, 1);                                                   \
        __builtin_amdgcn_s_setprio(0);                                      \
        __builtin_amdgcn_s_barrier();                                       \
    }

    STG(0, 0, 0, A, bm0);
    STG(0, 0, 1, A, bm0 + 128);
    STG(0, 0, 2, Wcat, bn0);
    STG(0, 0, 3, Wcat, bn0 + 128);
    STG(1, 1, 0, A, bm0);
    STG(1, 1, 2, Wcat, bn0);
    asm volatile("s_waitcnt vmcnt(4)" ::: "memory");
    __builtin_amdgcn_s_barrier();

    for (int t2 = 0; t2 < 7; ++t2) {
        const int T0 = t2 * 2;
        TILE(T0, 0, 4);
        TILE(T0 + 1, 1, 4);
    }
    TILE(14, 0, 0);
    TILE(15, 1, 0);

#undef TILE
#undef MFMA_PHASE
#undef LDB
#undef LDA
#undef STG

    const int which = bn0 >> 10;  // 0=q 1=k
    const float* bias = (which == 0) ? bq : bk;
    unsigned short* outp = (which == 0) ? qout : kout;
    const float scale = (which == 0) ? 0.1803368801111204f : 1.0f;  // 0.125*log2e
    const int nb = bn0 & 1023;

#pragma unroll
    for (int nh = 0; nh < 2; ++nh)
#pragma unroll
        for (int nf = 0; nf < 2; ++nf) {
            const int nl = nb + nh * 128 + wc * 32 + nf * 16 + lr;
            const float bvv = bias[nl];
            const int h = nl >> 6, hd = nl & 63;
#pragma unroll
            for (int mh = 0; mh < 2; ++mh)
#pragma unroll
                for (int mf = 0; mf < 4; ++mf) {
                    const f32x4 a = acc[mh * 4 + mf][nh * 2 + nf];
                    const int m0 = bm0 + mh * 128 + wr * 64 + mf * 16 + quad * 4;
                    const int b = m0 >> 11, t0 = m0 & 2047;
#pragma unroll
                    for (int r = 0; r < 4; ++r) {
                        outp[(((size_t)(b * Hh + h)) * Tt + t0 + r) * HDd + hd] =
                            f32_bf16_rn((a[r] + bvv) * scale);
                    }
                }
        }
}

// ---------------- V body: 256x128 2-phase (proj8 clone) ------------------
// Round-8: aregA/aregB double-buffer (+32 VGPR, safe: acc only 64 AGPR
// here) so LDA(1)'s 8-read burst flies during p1's MFMA; vmcnt moved
// before p2's MFMA.
__device__ __forceinline__ void v_body(
    unsigned short* lds, const int id,
    const unsigned short* __restrict__ A,
    const unsigned short* __restrict__ Wcat,
    const float* __restrict__ bv,
    unsigned short* __restrict__ vout) {
    const int tid  = threadIdx.x;
    const int wid  = tid >> 6;
    const int lane = tid & 63;
    const int quad = lane >> 4;
    const int lr   = lane & 15;
    const int wr   = wid >> 2;      // 0..1
    const int wc   = wid & 3;       // 0..3

    const int xcd  = id & 7;
    const int rank = id >> 3;
    const int by   = xcd * 4 + (rank >> 3);  // 0..31
    const int bx   = rank & 7;               // 0..7
    const int bm0  = by * 256;
    const int wrow0 = 2048 + bx * 128;       // row in Wcat

    const int srow  = wid * 8 + (lane >> 3);
    const int scol  = ((lane & 7) ^ (lane >> 3)) * 8;
    const int sldso = wid * 512;

    const int a_r   = wr * 64 + lr;
    const int b_r2  = (wc & 1) * 32 + lr;
    const int breg_off = 16384 + (wc >> 1) * 4096;
    const int slot0 = (quad ^ (lr & 7)) * 8;
    const int slot1 = ((quad ^ 4) ^ (lr & 7)) * 8;

    f32x4 acc[8][2];
    const f32x4 zero = {0.f, 0.f, 0.f, 0.f};
#pragma unroll
    for (int i = 0; i < 8; ++i)
#pragma unroll
        for (int j = 0; j < 2; ++j) acc[i][j] = zero;

    short8 aregA[4][2], aregB[4][2];
    short8 breg[2][2];

#define STGAV(S, BUF, REG_OFF, GROW)                                        \
    do {                                                                    \
        if ((S) < 16) {                                                     \
            unsigned short* lb = lds + (BUF) * 24576 + (REG_OFF) + sldso;   \
            const unsigned short* gp =                                      \
                A + (size_t)(bm0 + (GROW) + srow) * Cc + (S) * 64 + scol;   \
            ASYNC16(gp, lb);                                                \
            ASYNC16(gp + (size_t)64 * Cc, lb + 4096);                       \
        }                                                                   \
    } while (0)

#define STGBV(S, BUF, REG_OFF, NROW)                                        \
    do {                                                                    \
        if ((S) < 16) {                                                     \
            unsigned short* lb = lds + (BUF) * 24576 + (REG_OFF) + sldso;   \
            const unsigned short* gp =                                      \
                Wcat + (size_t)(wrow0 + (NROW) + srow) * Cc + (S) * 64 + scol; \
            ASYNC16(gp, lb);                                                \
        }                                                                   \
    } while (0)

#define LDA_V(DST, mh)                                                      \
    do {                                                                    \
        const unsigned short* ab = bufb + (mh) * 8192;                      \
        _Pragma("unroll") for (int mf = 0; mf < 4; ++mf) {                  \
            DST[mf][0] = *(const short8*)(ab + (a_r + mf * 16) * 64 + slot0); \
            DST[mf][1] = *(const short8*)(ab + (a_r + mf * 16) * 64 + slot1); \
        }                                                                   \
    } while (0)

#define LDB_V                                                               \
    do {                                                                    \
        const unsigned short* bb = bufb + breg_off;                         \
        _Pragma("unroll") for (int nf = 0; nf < 2; ++nf) {                  \
            breg[nf][0] = *(const short8*)(bb + (b_r2 + nf * 16) * 64 + slot0); \
            breg[nf][1] = *(const short8*)(bb + (b_r2 + nf * 16) * 64 + slot1); \
        }                                                                   \
    } while (0)

#define MFMA_V(AR, mh)                                                      \
    _Pragma("unroll") for (int mf = 0; mf < 4; ++mf)                        \
    _Pragma("unroll") for (int nf = 0; nf < 2; ++nf) {                      \
        acc[(mh)*4+mf][nf] = __builtin_amdgcn_mfma_f32_16x16x32_bf16(       \
            AR[mf][0], breg[nf][0], acc[(mh)*4+mf][nf], 0, 0, 0);           \
        acc[(mh)*4+mf][nf] = __builtin_amdgcn_mfma_f32_16x16x32_bf16(       \
            AR[mf][1], breg[nf][1], acc[(mh)*4+mf][nf], 0, 0, 0);           \
    }

// aregB reads region 8192 (A-h1 of T): staged at T-1 p1, resident via
// T-1's vmcnt(3)+barrier; drained by p2's MFMA before T+1's p1 STGAV
// overwrites it (>=1 barrier later).
#define TILE_V(T, BC, WN)                                                   \
    {                                                                       \
        const unsigned short* bufb = lds + (BC) * 24576;                    \
        LDA_V(aregA, 0);                                                    \
        LDB_V;                                                              \
        LDA_V(aregB, 1);                                                    \
        STGAV((T) + 1, (BC) ^ 1, 8192, 128);                                \
        STGBV((T) + 1, (BC) ^ 1, 20480, 64);                                \
        __builtin_amdgcn_s_barrier();                                       \
        __builtin_amdgcn_s_setprio(1);                                      \
        MFMA_V(aregA, 0);                                                   \
        __builtin_amdgcn_s_setprio(0);                                      \
        __builtin_amdgcn_s_barrier();                                       \
        STGAV((T) + 2, (BC), 0, 0);                                         \
        STGBV((T) + 2, (BC), 16384, 0);                                     \
        __builtin_amdgcn_s_barrier();                                       \
        asm volatile("s_waitcnt vmcnt(" #WN ")" ::: "memory");              \
        __builtin_amdgcn_s_setprio(1);                                      \
        MFMA_V(aregB, 1);                                                   \
        __builtin_amdgcn_s_setprio(0);                                      \
        __builtin_amdgcn_s_barrier();                                       \
    }

    STGAV(0, 0, 0, 0);
    STGAV(0, 0, 8192, 128);
    STGBV(0, 0, 16384, 0);
    STGBV(0, 0, 20480, 64);
    STGAV(1, 1, 0, 0);
    STGBV(1, 1, 16384, 0);
    asm volatile("s_waitcnt vmcnt(3)" ::: "memory");
    __builtin_amdgcn_s_barrier();

    for (int t2 = 0; t2 < 7; ++t2) {
        const int T0 = t2 * 2;
        TILE_V(T0, 0, 3);
        TILE_V(T0 + 1, 1, 3);
    }
    TILE_V(14, 0, 0);
    TILE_V(15, 1, 0);

#undef TILE_V
#undef MFMA_V
#undef LDB_V
#undef LDA_V
#undef STGBV
#undef STGAV

    // v epilogue: bf16 [B,H,HD,T], ushort4 along T
#pragma unroll
    for (int nf = 0; nf < 2; ++nf) {
        const int nl = (wrow0 - 2048) + wc * 32 + nf * 16 + lr;  // 0..1023
        const float bvv = bv[nl];
        const int h = nl >> 6, hd = nl & 63;
#pragma unroll
        for (int mh = 0; mh < 2; ++mh)
#pragma unroll
            for (int mf = 0; mf < 4; ++mf) {
                const f32x4 a = acc[mh * 4 + mf][nf];
                const int m0 = bm0 + mh * 128 + wr * 64 + mf * 16 + quad * 4;
                const int b = m0 >> 11, t0 = m0 & 2047;
                ushort4 pk;
                pk.x = f32_bf16_rn(a[0] + bvv);
                pk.y = f32_bf16_rn(a[1] + bvv);
                pk.z = f32_bf16_rn(a[2] + bvv);
                pk.w = f32_bf16_rn(a[3] + bvv);
                *(ushort4*)(vout + (((size_t)(b * Hh + h)) * HDd + hd) * Tt + t0) = pk;
            }
    }
}

// ---------------- fused QKV: one launch, 512 blocks ----------------------
__global__ __launch_bounds__(512, 2) void gemm_fused(
    const unsigned short* __restrict__ A,
    const unsigned short* __restrict__ Wcat,
    const float* __restrict__ bq, const float* __restrict__ bk,
    const float* __restrict__ bv,
    unsigned short* __restrict__ qout, unsigned short* __restrict__ kout,
    unsigned short* __restrict__ vout) {
    extern __shared__ unsigned short lds[];
    const int id = blockIdx.y * 8 + blockIdx.x;  // grid (8,64): 0..511
    if (id < 256)
        qk_body(lds, id, A, Wcat, bq, bk, qout, kout);
    else
        v_body(lds, id - 256, A, Wcat, bv, vout);
}

// ---------------- output projection GEMM: 256x128 2-phase template -------
// Round-8: same read/MFMA overlap as v_body (aregA/aregB + hoisted
// LDA(1) + vmcnt before p2 MFMA).
__global__ __launch_bounds__(512, 2) void gemm_proj8(
    const unsigned short* __restrict__ A,
    const unsigned short* __restrict__ W,
    const float* __restrict__ bias,
    float* __restrict__ out) {
    extern __shared__ unsigned short lds[];

    const int tid  = threadIdx.x;
    const int wid  = tid >> 6;
    const int lane = tid & 63;
    const int quad = lane >> 4;
    const int lr   = lane & 15;
    const int wr   = wid >> 2;      // 0..1
    const int wc   = wid & 3;       // 0..3

    const int id   = blockIdx.y * 8 + blockIdx.x;
    const int xcd  = id & 7;
    const int rank = id >> 3;          // 0..31
    const int by   = xcd * 4 + (rank >> 3);  // 0..31
    const int bx   = rank & 7;               // 0..7
    const int bm0  = by * 256;
    const int bn0  = bx * 128;

    const int srow  = wid * 8 + (lane >> 3);
    const int scol  = ((lane & 7) ^ (lane >> 3)) * 8;
    const int sldso = wid * 512;

    const int a_r   = wr * 64 + lr;
    const int b_r2  = (wc & 1) * 32 + lr;     // row within own B region
    const int breg_off = 16384 + (wc >> 1) * 4096;  // wave's B region
    const int slot0 = (quad ^ (lr & 7)) * 8;
    const int slot1 = ((quad ^ 4) ^ (lr & 7)) * 8;

    f32x4 acc[8][2];
    const f32x4 zero = {0.f, 0.f, 0.f, 0.f};
#pragma unroll
    for (int i = 0; i < 8; ++i)
#pragma unroll
        for (int j = 0; j < 2; ++j) acc[i][j] = zero;

    short8 aregA[4][2], aregB[4][2];
    short8 breg[2][2];

#define STGA(S, BUF, REG_OFF, GROW)                                         \
    do {                                                                    \
        if ((S) < 16) {                                                     \
            unsigned short* lb = lds + (BUF) * 24576 + (REG_OFF) + sldso;   \
            const unsigned short* gp =                                      \
                A + (size_t)(bm0 + (GROW) + srow) * Cc + (S) * 64 + scol;   \
            ASYNC16(gp, lb);                                                \
            ASYNC16(gp + (size_t)64 * Cc, lb + 4096);                       \
        }                                                                   \
    } while (0)

#define STGB(S, BUF, REG_OFF, NROW)                                         \
    do {                                                                    \
        if ((S) < 16) {                                                     \
            unsigned short* lb = lds + (BUF) * 24576 + (REG_OFF) + sldso;   \
            const unsigned short* gp =                                      \
                W + (size_t)(bn0 + (NROW) + srow) * Cc + (S) * 64 + scol;   \
            ASYNC16(gp, lb);                                                \
        }                                                                   \
    } while (0)

#define LDA_P(DST, mh)                                                      \
    do {                                                                    \
        const unsigned short* ab = bufb + (mh) * 8192;                      \
        _Pragma("unroll") for (int mf = 0; mf < 4; ++mf) {                  \
            DST[mf][0] = *(const short8*)(ab + (a_r + mf * 16) * 64 + slot0); \
            DST[mf][1] = *(const short8*)(ab + (a_r + mf * 16) * 64 + slot1); \
        }                                                                   \
    } while (0)

#define LDB_P                                                               \
    do {                                                                    \
        const unsigned short* bb = bufb + breg_off;                         \
        _Pragma("unroll") for (int nf = 0; nf < 2; ++nf) {                  \
            breg[nf][0] = *(const short8*)(bb + (b_r2 + nf * 16) * 64 + slot0); \
            breg[nf][1] = *(const short8*)(bb + (b_r2 + nf * 16) * 64 + slot1); \
        }                                                                   \
    } while (0)

#define MFMA_P(AR, mh)                                                      \
    _Pragma("unroll") for (int mf = 0; mf < 4; ++mf)                        \
    _Pragma("unroll") for (int nf = 0; nf < 2; ++nf) {                      \
        acc[(mh)*4+mf][nf] = __builtin_amdgcn_mfma_f32_16x16x32_bf16(       \
            AR[mf][0], breg[nf][0], acc[(mh)*4+mf][nf], 0, 0, 0);           \
        acc[(mh)*4+mf][nf] = __builtin_amdgcn_mfma_f32_16x16x32_bf16(       \
            AR[mf][1], breg[nf][1], acc[(mh)*4+mf][nf], 0, 0, 0);           \
    }

#define TILE_P(T, BC, WN)                                                   \
    {                                                                       \
        const unsigned short* bufb = lds + (BC) * 24576;                    \
        LDA_P(aregA, 0);                                                    \
        LDB_P;                                                              \
        LDA_P(aregB, 1);                                                    \
        STGA((T) + 1, (BC) ^ 1, 8192, 128);                                 \
        STGB((T) + 1, (BC) ^ 1, 20480, 64);                                 \
        __builtin_amdgcn_s_barrier();                                       \
        __builtin_amdgcn_s_setprio(1);                                      \
        MFMA_P(aregA, 0);                                                   \
        __builtin_amdgcn_s_setprio(0);                                      \
        __builtin_amdgcn_s_barrier();                                       \
        STGA((T) + 2, (BC), 0, 0);                                          \
        STGB((T) + 2, (BC), 16384, 0);                                      \
        __builtin_amdgcn_s_barrier();                                       \
        asm volatile("s_waitcnt vmcnt(" #WN ")" ::: "memory");              \
        __builtin_amdgcn_s_setprio(1);                                      \
        MFMA_P(aregB, 1);                                                   \
        __builtin_amdgcn_s_setprio(0);                                      \
        __builtin_amdgcn_s_barrier();                                       \
    }

    STGA(0, 0, 0, 0);
    STGA(0, 0, 8192, 128);
    STGB(0, 0, 16384, 0);
    STGB(0, 0, 20480, 64);
    STGA(1, 1, 0, 0);
    STGB(1, 1, 16384, 0);
    asm volatile("s_waitcnt vmcnt(3)" ::: "memory");
    __builtin_amdgcn_s_barrier();

    for (int t2 = 0; t2 < 7; ++t2) {
        const int T0 = t2 * 2;
        TILE_P(T0, 0, 3);
        TILE_P(T0 + 1, 1, 3);
    }
    TILE_P(14, 0, 0);
    TILE_P(15, 1, 0);

#undef TILE_P
#undef MFMA_P
#undef LDB_P
#undef LDA_P
#undef STGB
#undef STGA

#pragma unroll
    for (int nf = 0; nf < 2; ++nf) {
        const int n = bn0 + wc * 32 + nf * 16 + lr;
        const float bvv = bias[n];
#pragma unroll
        for (int mh = 0; mh < 2; ++mh)
#pragma unroll
            for (int mf = 0; mf < 4; ++mf) {
                const f32x4 a = acc[mh * 4 + mf][nf];
                const int m0 = bm0 + mh * 128 + wr * 64 + mf * 16 + quad * 4;
#pragma unroll
                for (int r = 0; r < 4; ++r)
                    out[(size_t)(m0 + r) * Cc + n] = a[r] + bvv;
            }
    }
}

// ---------------- flash attention: 32x32 MFMA, 4 blocks/CU ---------------
// (unchanged from round 7 — verified)
__global__ __launch_bounds__(256, 4) void attn(const unsigned short* __restrict__ q,
                                               const unsigned short* __restrict__ k,
                                               const unsigned short* __restrict__ vt,
                                               unsigned short* __restrict__ y) {
    __shared__ unsigned short sK[2][64 * 64];
    __shared__ unsigned short sV[2][64 * 64];

    const int tid  = threadIdx.x;
    const int wid  = tid >> 6;
    const int lane = tid & 63;
    const int l31  = lane & 31;
    const int hb   = lane >> 5;       // half-wave
    const int x7   = lane & 7;

    const int bh = blockIdx.x;        // head
    const int yb = blockIdx.y;        // 0..15
    const int qt = (yb & 4) ? ((yb & 8) ? yb - 12 : yb + 4) : 15 - yb;
    const size_t headq = (size_t)bh * Tt * HDd;
    const unsigned short* kg = k + headq;
    const unsigned short* vg = vt + headq;
    const int b = bh >> 4, h = bh & 15;

    const int g_r = lane >> 3;                       // 0..7
    const int g_c = ((lane & 7) ^ g_r) * 8;          // pre-swizzled src col
    const unsigned short* kst = kg + (size_t)(wid * 16 + g_r) * HDd + g_c;
    const unsigned short* vst = vg + (size_t)(wid * 16 + g_r) * Tt + g_c;
    unsigned short* dK0 = sK[0] + wid * 1024;
    unsigned short* dK1 = sK[1] + wid * 1024;
    unsigned short* dV0 = sV[0] + wid * 1024;
    unsigned short* dV1 = sV[1] + wid * 1024;

#define STAGE_KV(BUF, KB)                                                   \
    do {                                                                    \
        unsigned short* dK = (BUF) ? dK1 : dK0;                             \
        unsigned short* dV = (BUF) ? dV1 : dV0;                             \
        ASYNC16(kst + (size_t)(KB) * HDd,       dK);                        \
        ASYNC16(kst + (size_t)((KB) + 8) * HDd, dK + 512);                  \
        ASYNC16(vst + (KB),                     dV);                        \
        ASYNC16(vst + (size_t)8 * Tt + (KB),    dV + 512);                  \
    } while (0)

#define CVTPK(d, a, bb) asm("v_cvt_pk_bf16_f32 %0, %1, %2" : "=v"(d) : "v"(a), "v"(bb))
#define PLSWAP(xx, yy)  asm("v_permlane32_swap_b32 %0, %1" : "+v"(xx), "+v"(yy))

    const int frow = l31 * 64;

    const f32x16 zero16 = {0.f,0.f,0.f,0.f,0.f,0.f,0.f,0.f,
                           0.f,0.f,0.f,0.f,0.f,0.f,0.f,0.f};

    const int qb = qt * 128;
    const int ntiles = 2 * qt + 2;
    const int nw = 2 * qt + 1 + (wid >> 1);   // per-wave active tiles

    const unsigned short* qp =
        q + headq + (size_t)(qb + wid * 32 + l31) * HDd;
    short8 qf[4];
#pragma unroll
    for (int c = 0; c < 4; c++)
        qf[c] = *(const short8*)(qp + c * 16 + hb * 8);

    f32x16 o0 = zero16, o1 = zero16;
    float l_run = 0.f;

    STAGE_KV(0, 0);
    __syncthreads();

    for (int kt = 0; kt < ntiles; ++kt) {
        const int cur = kt & 1;
        if (kt + 1 < ntiles) STAGE_KV(cur ^ 1, (kt + 1) * 64);

        if (kt < nw) {
            const unsigned short* bK = sK[cur];
            const unsigned short* bV = sV[cur];

            // QK^T swapped: p0 (k 0..31), p1 (k 32..63)
            f32x16 p0 = zero16, p1 = zero16;
            __builtin_amdgcn_s_setprio(1);
#pragma unroll
            for (int c = 0; c < 4; c++) {
                const int cs = ((2 * c + hb) ^ x7) * 8;
                short8 kf0 = *(const short8*)(bK + frow + cs);
                short8 kf1 = *(const short8*)(bK + 2048 + frow + cs);
                p0 = __builtin_amdgcn_mfma_f32_32x32x16_bf16(kf0, qf[c], p0, 0, 0, 0);
                p1 = __builtin_amdgcn_mfma_f32_32x32x16_bf16(kf1, qf[c], p1, 0, 0, 0);
            }
            __builtin_amdgcn_s_setprio(0);

            // causal mask (only the diagonal tile)
            if (kt == nw - 1 || kt == ntiles - 1) {
                const int qd = qb + wid * 32 + l31 - kt * 64 - 4 * hb;
#pragma unroll
                for (int r = 0; r < 16; r++) {
                    const int kb0 = (r & 3) + 8 * (r >> 2);
                    p0[r] = (kb0 <= qd) ? p0[r] : -INFINITY;
                    p1[r] = (kb0 + 32 <= qd) ? p1[r] : -INFINITY;
                }
            }

            // exp2 + row-sum (in-lane) + pack pairs
            float lacc = 0.f;
#pragma unroll
            for (int r = 0; r < 16; r++) {
                p0[r] = fast_exp2(p0[r]); lacc += p0[r];
                p1[r] = fast_exp2(p1[r]); lacc += p1[r];
            }
            l_run += lacc;

            unsigned w0[4][2], w1[4][2];
#pragma unroll
            for (int g = 0; g < 4; g++) {
                CVTPK(w0[g][0], p0[4 * g + 0], p0[4 * g + 1]);
                CVTPK(w0[g][1], p0[4 * g + 2], p0[4 * g + 3]);
                CVTPK(w1[g][0], p1[4 * g + 0], p1[4 * g + 1]);
                CVTPK(w1[g][1], p1[4 * g + 2], p1[4 * g + 3]);
            }

            // PV: per k-16 chunk kc: A-frag via permlane32_swap, B = V
            __builtin_amdgcn_s_setprio(1);
#pragma unroll
            for (int kc = 0; kc < 4; kc++) {
                unsigned x0, x1, y0, y1;
                if (kc == 0)      { x0 = w0[0][0]; x1 = w0[0][1]; y0 = w0[1][0]; y1 = w0[1][1]; }
                else if (kc == 1) { x0 = w0[2][0]; x1 = w0[2][1]; y0 = w0[3][0]; y1 = w0[3][1]; }
                else if (kc == 2) { x0 = w1[0][0]; x1 = w1[0][1]; y0 = w1[1][0]; y1 = w1[1][1]; }
                else              { x0 = w1[2][0]; x1 = w1[2][1]; y0 = w1[3][0]; y1 = w1[3][1]; }
                PLSWAP(x0, y0);
                PLSWAP(x1, y1);
                union { unsigned u[4]; short8 s; } pu;
                pu.u[0] = x0; pu.u[1] = x1; pu.u[2] = y0; pu.u[3] = y1;

                const int vs = ((2 * kc + hb) ^ x7) * 8;
                short8 vf0 = *(const short8*)(bV + frow + vs);
                short8 vf1 = *(const short8*)(bV + 2048 + frow + vs);
                o0 = __builtin_amdgcn_mfma_f32_32x32x16_bf16(pu.s, vf0, o0, 0, 0, 0);
                o1 = __builtin_amdgcn_mfma_f32_32x32x16_bf16(pu.s, vf1, o1, 0, 0, 0);
            }
            __builtin_amdgcn_s_setprio(0);
        }

        __syncthreads();
    }

    // normalize + write
    l_run += __shfl_xor(l_run, 32);
    const float inv = 1.0f / l_run;
    unsigned short* yp = y + (size_t)(b * Tt + qb + wid * 32) * Cc + h * HDd;
#pragma unroll
    for (int r = 0; r < 16; r++) {
        const int qr = (r & 3) + 8 * (r >> 2) + 4 * hb;
        const float invr = __shfl(inv, qr);
        yp[(size_t)qr * Cc + l31]      = f32_bf16_rn(o0[r] * invr);
        yp[(size_t)qr * Cc + 32 + l31] = f32_bf16_rn(o1[r] * invr);
    }
#undef STAGE_KV
#undef CVTPK
#undef PLSWAP
}

// ---------------- launch ----------------
extern "C" void kernel_launch(void* const* d_in, const int* in_sizes, int n_in,
                              void* d_out, int out_size, void* d_ws, size_t ws_size,
                              hipStream_t stream) {
    const float* x  = (const float*)d_in[0];
    const float* Wk = (const float*)d_in[1];
    const float* bk = (const float*)d_in[2];
    const float* Wq = (const float*)d_in[3];
    const float* bq = (const float*)d_in[4];
    const float* Wv = (const float*)d_in[5];
    const float* bv = (const float*)d_in[6];
    const float* Wp = (const float*)d_in[7];
    const float* bp = (const float*)d_in[8];
    float* out = (float*)d_out;

    char* ws = (char*)d_ws;
    size_t off = 0;
    auto alloc = [&](size_t bytes) { char* p = ws + off; off += bytes; return p; };
    const size_t MK = (size_t)8192 * 1024;
    const size_t NK = (size_t)1024 * 1024;
    unsigned short* xb   = (unsigned short*)alloc(MK * 2);
    unsigned short* Wcat = (unsigned short*)alloc(3 * NK * 2);  // q|k|v contiguous
    unsigned short* Wqb  = Wcat;
    unsigned short* Wkb  = Wcat + NK;
    unsigned short* Wvb  = Wcat + 2 * NK;
    unsigned short* Wpb  = (unsigned short*)alloc(NK * 2);
    unsigned short* qh   = (unsigned short*)alloc(MK * 2);  // [B,H,T,HD], pre-scaled
    unsigned short* kh   = (unsigned short*)alloc(MK * 2);  // [B,H,T,HD]
    unsigned short* vth  = (unsigned short*)alloc(MK * 2);  // [B,H,HD,T]
    unsigned short* ya   = (unsigned short*)alloc(MK * 2);  // [B,T,C]

    static bool lds_attr_set = false;
    if (!lds_attr_set) {
        (void)hipFuncSetAttribute((const void*)gemm_fused,
                                  hipFuncAttributeMaxDynamicSharedMemorySize,
                                  131072);
        (void)hipFuncSetAttribute((const void*)gemm_proj8,
                                  hipFuncAttributeMaxDynamicSharedMemorySize,
                                  98304);
        lds_attr_set = true;
    }

    cvt_all<<<12288, 256, 0, stream>>>(x, Wq, Wk, Wv, Wp, xb, Wqb, Wkb, Wvb, Wpb);

    gemm_fused<<<dim3(8, 64), 512, 131072, stream>>>(xb, Wcat, bq, bk, bv, qh, kh, vth);

    attn<<<dim3(64, 16), 256, 0, stream>>>(qh, kh, vth, ya);

    gemm_proj8<<<dim3(8, 32), 512, 98304, stream>>>(ya, Wpb, bp, out);
}